// Round 2
// baseline (132.189 us; speedup 1.0000x reference)
//
#include <hip/hip_runtime.h>
#include <math.h>

#define NPAIRS 262144
#define D4     32        // 128 floats = 32 float4 per row
#define TPB    256
#define NBLK   2048      // 2048 blocks * 8 groups = 16384 groups; NPAIRS/16384 = 16 pairs/group/list

// One 32-lane group per pair: lane l loads float4 #l of each row (coalesced
// 512B per row). Pos pairs: squared distance is separable over dims -> each
// lane accumulates its own partial across ALL its pos pairs; one reduction at
// the end (no per-pair shuffles). Neg pairs: per-pair butterfly reduce, but 4
// pairs unrolled so the 4 shuffle chains pipeline. 4 idx->gather chains in
// flight per group for latency hiding.
__global__ __launch_bounds__(TPB) void pair_kernel(
    const float* __restrict__ X,
    const int2*  __restrict__ pos2,
    const int2*  __restrict__ neg2,
    const float* __restrict__ h_bias,
    float* __restrict__ out)
{
    const int lane    = threadIdx.x & 31;
    const int group   = threadIdx.x >> 5;
    const int gid     = (blockIdx.x * TPB + threadIdx.x) >> 5;
    const int ngroups = (gridDim.x * TPB) >> 5;   // 16384 at NBLK=2048

    const float4* __restrict__ X4 = (const float4*)X;

    // numerically stable softplus(h_bias)
    const float hb   = h_bias[0];
    const float bias = fmaxf(hb, 0.0f) + log1pf(expf(-fabsf(hb)));

    // ---------------- positive pairs: no per-pair reduction ----------------
    float posAcc = 0.0f;
    for (int p = gid; p < NPAIRS; p += 4 * ngroups) {
        const int2 ij0 = pos2[p];
        const int2 ij1 = pos2[p +     ngroups];
        const int2 ij2 = pos2[p + 2 * ngroups];
        const int2 ij3 = pos2[p + 3 * ngroups];
        const float4 a0 = X4[ij0.x * D4 + lane], b0 = X4[ij0.y * D4 + lane];
        const float4 a1 = X4[ij1.x * D4 + lane], b1 = X4[ij1.y * D4 + lane];
        const float4 a2 = X4[ij2.x * D4 + lane], b2 = X4[ij2.y * D4 + lane];
        const float4 a3 = X4[ij3.x * D4 + lane], b3 = X4[ij3.y * D4 + lane];
        float d;
        d = a0.x - b0.x; posAcc = fmaf(d, d, posAcc);
        d = a0.y - b0.y; posAcc = fmaf(d, d, posAcc);
        d = a0.z - b0.z; posAcc = fmaf(d, d, posAcc);
        d = a0.w - b0.w; posAcc = fmaf(d, d, posAcc);
        d = a1.x - b1.x; posAcc = fmaf(d, d, posAcc);
        d = a1.y - b1.y; posAcc = fmaf(d, d, posAcc);
        d = a1.z - b1.z; posAcc = fmaf(d, d, posAcc);
        d = a1.w - b1.w; posAcc = fmaf(d, d, posAcc);
        d = a2.x - b2.x; posAcc = fmaf(d, d, posAcc);
        d = a2.y - b2.y; posAcc = fmaf(d, d, posAcc);
        d = a2.z - b2.z; posAcc = fmaf(d, d, posAcc);
        d = a2.w - b2.w; posAcc = fmaf(d, d, posAcc);
        d = a3.x - b3.x; posAcc = fmaf(d, d, posAcc);
        d = a3.y - b3.y; posAcc = fmaf(d, d, posAcc);
        d = a3.z - b3.z; posAcc = fmaf(d, d, posAcc);
        d = a3.w - b3.w; posAcc = fmaf(d, d, posAcc);
    }

    // ---------------- negative pairs: per-pair reduce, 4-way unrolled ------
    float negAcc = 0.0f;
    for (int p = gid; p < NPAIRS; p += 4 * ngroups) {
        const int2 ij0 = neg2[p];
        const int2 ij1 = neg2[p +     ngroups];
        const int2 ij2 = neg2[p + 2 * ngroups];
        const int2 ij3 = neg2[p + 3 * ngroups];
        const float4 a0 = X4[ij0.x * D4 + lane], b0 = X4[ij0.y * D4 + lane];
        const float4 a1 = X4[ij1.x * D4 + lane], b1 = X4[ij1.y * D4 + lane];
        const float4 a2 = X4[ij2.x * D4 + lane], b2 = X4[ij2.y * D4 + lane];
        const float4 a3 = X4[ij3.x * D4 + lane], b3 = X4[ij3.y * D4 + lane];
        float d;
        float s0 = 0.f, s1 = 0.f, s2 = 0.f, s3 = 0.f;
        d = a0.x - b0.x; s0 = fmaf(d, d, s0);
        d = a0.y - b0.y; s0 = fmaf(d, d, s0);
        d = a0.z - b0.z; s0 = fmaf(d, d, s0);
        d = a0.w - b0.w; s0 = fmaf(d, d, s0);
        d = a1.x - b1.x; s1 = fmaf(d, d, s1);
        d = a1.y - b1.y; s1 = fmaf(d, d, s1);
        d = a1.z - b1.z; s1 = fmaf(d, d, s1);
        d = a1.w - b1.w; s1 = fmaf(d, d, s1);
        d = a2.x - b2.x; s2 = fmaf(d, d, s2);
        d = a2.y - b2.y; s2 = fmaf(d, d, s2);
        d = a2.z - b2.z; s2 = fmaf(d, d, s2);
        d = a2.w - b2.w; s2 = fmaf(d, d, s2);
        d = a3.x - b3.x; s3 = fmaf(d, d, s3);
        d = a3.y - b3.y; s3 = fmaf(d, d, s3);
        d = a3.z - b3.z; s3 = fmaf(d, d, s3);
        d = a3.w - b3.w; s3 = fmaf(d, d, s3);
        // 4 independent butterfly chains -> pipelined ds ops
        #pragma unroll
        for (int m = 16; m > 0; m >>= 1) {
            s0 += __shfl_xor(s0, m, 32);
            s1 += __shfl_xor(s1, m, 32);
            s2 += __shfl_xor(s2, m, 32);
            s3 += __shfl_xor(s3, m, 32);
        }
        float t;
        t = fmaxf(bias - sqrtf(s0), 0.f); negAcc = fmaf(t, t, negAcc);
        t = fmaxf(bias - sqrtf(s1), 0.f); negAcc = fmaf(t, t, negAcc);
        t = fmaxf(bias - sqrtf(s2), 0.f); negAcc = fmaf(t, t, negAcc);
        t = fmaxf(bias - sqrtf(s3), 0.f); negAcc = fmaf(t, t, negAcc);
    }
    // negAcc is group-uniform (every lane accumulated identical values).

    // reduce posAcc across the 32-lane group
    #pragma unroll
    for (int m = 16; m > 0; m >>= 1) posAcc += __shfl_xor(posAcc, m, 32);

    __shared__ float sp[TPB / 32], sn[TPB / 32];
    if (lane == 0) { sp[group] = posAcc; sn[group] = negAcc; }
    __syncthreads();
    if (threadIdx.x == 0) {
        float P = 0.f, Nn = 0.f;
        #pragma unroll
        for (int g = 0; g < TPB / 32; ++g) { P += sp[g]; Nn += sn[g]; }
        atomicAdd(&out[0], P  * (0.5f / NPAIRS));
        atomicAdd(&out[1], Nn * (0.5f / NPAIRS));
    }
}

extern "C" void kernel_launch(void* const* d_in, const int* in_sizes, int n_in,
                              void* d_out, int out_size, void* d_ws, size_t ws_size,
                              hipStream_t stream) {
    const float* X       = (const float*)d_in[0];
    // d_in[1] = scores (unused), d_in[3] = labels (unused)
    const float* h_bias  = (const float*)d_in[2];
    const int2*  pos2    = (const int2*)d_in[4];
    const int2*  neg2    = (const int2*)d_in[5];
    float*       out     = (float*)d_out;

    hipMemsetAsync(out, 0, (size_t)out_size * sizeof(float), stream);
    pair_kernel<<<NBLK, TPB, 0, stream>>>(X, pos2, neg2, h_bias, out);
}